// Round 6
// baseline (262.321 us; speedup 1.0000x reference)
//
#include <hip/hip_runtime.h>

#define ALPHA 0.002
#define NBLK 2048   // 8 blocks/CU on 256 CUs — all resident at 64 VGPR
#define BLK  256

typedef float fx4 __attribute__((ext_vector_type(4)));

// Single fused kernel, full-occupancy version.
// Phase 1: tid<64 redundantly compute P = M^100 and Q = ALPHA*sum M^k
//          (M = I - ALPHA*A) via binary doubling in fp64 (bits(100)=1100100),
//          publish fp32 sP/sQ in LDS. Barriers are uniform (bits compile-time).
// Phase 2: grid-stride streaming, register double-buffer:
//          out[row] = x[row]*P + y[row]*Q.
// __launch_bounds__(256, 8): cap VGPR at 64 so all 8 waves/SIMD are resident
// (round-5 build used 88 VGPR -> 5 waves/SIMD, 5/8 of intended TLP + a
// 768-block second scheduling round that redid the PQ phase on the tail).
__global__ __launch_bounds__(BLK, 8) void fused_apply(const fx4* __restrict__ x4,
                                                      const fx4* __restrict__ y4,
                                                      const float* __restrict__ A,
                                                      fx4* __restrict__ out4,
                                                      int nrows) {
    __shared__ double Ms[64];
    __shared__ double Ps[64];
    __shared__ double Ss[64];
    __shared__ float sP[64];
    __shared__ float sQ[64];

    const int tid = threadIdx.x;
    const int stride = NBLK * BLK;

    // ---- Phase 1: per-block P/Q via binary doubling (tid<64 active) ----
    const int i = tid >> 3, j = tid & 7;
    if (tid < 64)
        Ms[tid] = ((i == j) ? 1.0 : 0.0) - (double)ALPHA * (double)A[tid];
    __syncthreads();

    double Mcol[8];
    if (tid < 64) {
#pragma unroll
        for (int t = 0; t < 8; ++t) Mcol[t] = Ms[t * 8 + j];
    }

    double P = (i == j) ? 1.0 : 0.0;  // garbage for tid>=64, unused
    double S = 0.0;
    const int bits[7] = {1, 1, 0, 0, 1, 0, 0};  // 100 = 0b1100100

#pragma unroll
    for (int b = 0; b < 7; ++b) {
        if (tid < 64) { Ps[tid] = P; Ss[tid] = S; }
        __syncthreads();
        double accS = S, accP = 0.0;
        if (tid < 64) {
#pragma unroll
            for (int t = 0; t < 8; ++t) {
                const double pit = Ps[i * 8 + t];
                accS += pit * Ss[t * 8 + j];   // S + P*S
                accP += pit * Ps[t * 8 + j];   // P*P
            }
        }
        __syncthreads();
        if (bits[b]) {
            if (tid < 64) { S = accS + accP; Ps[tid] = accP; }
            __syncthreads();
            if (tid < 64) {
                double p2 = 0.0;
#pragma unroll
                for (int t = 0; t < 8; ++t) p2 += Ps[i * 8 + t] * Mcol[t];
                P = p2;
            }
            __syncthreads();
        } else {
            S = accS;
            P = accP;
        }
    }

    if (tid < 64) {
        sP[tid] = (float)P;
        sQ[tid] = (float)((double)ALPHA * S);
    }
    __syncthreads();

    // ---- Phase 2: streaming with register double-buffer ----
    int row = blockIdx.x * BLK + tid;          // < nrows (524288 < 2M)
    size_t p = (size_t)row * 2;
    fx4 cx0 = x4[p], cx1 = x4[p + 1];
    fx4 cy0 = y4[p], cy1 = y4[p + 1];

    for (;;) {
        const int nrow = row + stride;
        const bool more = (nrow < nrows);
        fx4 nx0, nx1, ny0, ny1;
        if (more) {
            const size_t np = (size_t)nrow * 2;
            nx0 = x4[np]; nx1 = x4[np + 1];
            ny0 = y4[np]; ny1 = y4[np + 1];
        }

        const float xs[8] = {cx0.x, cx0.y, cx0.z, cx0.w,
                             cx1.x, cx1.y, cx1.z, cx1.w};
        const float ys[8] = {cy0.x, cy0.y, cy0.z, cy0.w,
                             cy1.x, cy1.y, cy1.z, cy1.w};
        float ov[8];
#pragma unroll
        for (int jj = 0; jj < 8; ++jj) {
            float acc = 0.0f;
#pragma unroll
            for (int t = 0; t < 8; ++t) acc = fmaf(xs[t], sP[t * 8 + jj], acc);
#pragma unroll
            for (int t = 0; t < 8; ++t) acc = fmaf(ys[t], sQ[t * 8 + jj], acc);
            ov[jj] = acc;
        }
        fx4 o0 = {ov[0], ov[1], ov[2], ov[3]};
        fx4 o1 = {ov[4], ov[5], ov[6], ov[7]};
        out4[p]     = o0;
        out4[p + 1] = o1;

        if (!more) break;
        row = nrow;
        p = (size_t)row * 2;
        cx0 = nx0; cx1 = nx1; cy0 = ny0; cy1 = ny1;
    }
}

extern "C" void kernel_launch(void* const* d_in, const int* in_sizes, int n_in,
                              void* d_out, int out_size, void* d_ws, size_t ws_size,
                              hipStream_t stream) {
    const float* x = (const float*)d_in[0];
    const float* y = (const float*)d_in[1];
    const float* A = (const float*)d_in[2];
    float* out = (float*)d_out;

    const int nrows = in_sizes[0] / 8;  // 2,000,000

    fused_apply<<<NBLK, BLK, 0, stream>>>((const fx4*)x, (const fx4*)y, A,
                                          (fx4*)out, nrows);
}

// Round 7
// 36.824 us; speedup vs baseline: 7.1236x; 7.1236x over previous
//
#include <hip/hip_runtime.h>

#define ALPHA 0.002
#define NBLK 1280   // 5 blocks/CU on 256 CUs — ALL resident at 88 VGPR
#define BLK  256

typedef float fx4 __attribute__((ext_vector_type(4)));

// Single fused kernel (round-5 structure, grid sized to real residency).
// Phase 0: each thread issues its first row's x/y loads (kept in flight).
// Phase 1: tid<64 redundantly compute P = M^100 and Q = ALPHA*sum M^k
//          (M = I - ALPHA*A) via binary doubling in fp64 (bits(100)=1100100),
//          publish fp32 sP/sQ in LDS. Barriers uniform (bits compile-time).
// Phase 2: grid-stride streaming, register double-buffer:
//          out[row] = x[row]*P + y[row]*Q.
// NOTE: no min-waves launch_bounds — forcing 8 waves/SIMD (64 VGPR) made the
// allocator spill everything to scratch (R6: 750 MB of spill traffic, 7x
// slowdown). 88 VGPR -> 5 waves/SIMD; NBLK=1280 matches that exactly.
__global__ __launch_bounds__(BLK) void fused_apply(const fx4* __restrict__ x4,
                                                   const fx4* __restrict__ y4,
                                                   const float* __restrict__ A,
                                                   fx4* __restrict__ out4,
                                                   int nrows) {
    __shared__ double Ms[64];
    __shared__ double Ps[64];
    __shared__ double Ss[64];
    __shared__ float sP[64];
    __shared__ float sQ[64];

    const int tid = threadIdx.x;
    const int stride = NBLK * BLK;

    // ---- Phase 0: issue first row's loads early (hide PQ latency) ----
    int row = blockIdx.x * BLK + tid;          // < nrows (327680 < 2M)
    size_t p = (size_t)row * 2;
    fx4 cx0 = x4[p], cx1 = x4[p + 1];
    fx4 cy0 = y4[p], cy1 = y4[p + 1];

    // ---- Phase 1: per-block P/Q via binary doubling (tid<64 active) ----
    const int i = tid >> 3, j = tid & 7;
    if (tid < 64)
        Ms[tid] = ((i == j) ? 1.0 : 0.0) - (double)ALPHA * (double)A[tid];
    __syncthreads();

    double Mcol[8];
    if (tid < 64) {
#pragma unroll
        for (int t = 0; t < 8; ++t) Mcol[t] = Ms[t * 8 + j];
    }

    double P = (i == j) ? 1.0 : 0.0;  // garbage for tid>=64, unused
    double S = 0.0;
    const int bits[7] = {1, 1, 0, 0, 1, 0, 0};  // 100 = 0b1100100

#pragma unroll
    for (int b = 0; b < 7; ++b) {
        if (tid < 64) { Ps[tid] = P; Ss[tid] = S; }
        __syncthreads();
        double accS = S, accP = 0.0;
        if (tid < 64) {
#pragma unroll
            for (int t = 0; t < 8; ++t) {
                const double pit = Ps[i * 8 + t];
                accS += pit * Ss[t * 8 + j];   // S + P*S
                accP += pit * Ps[t * 8 + j];   // P*P
            }
        }
        __syncthreads();
        if (bits[b]) {
            if (tid < 64) { S = accS + accP; Ps[tid] = accP; }
            __syncthreads();
            if (tid < 64) {
                double p2 = 0.0;
#pragma unroll
                for (int t = 0; t < 8; ++t) p2 += Ps[i * 8 + t] * Mcol[t];
                P = p2;
            }
            __syncthreads();
        } else {
            S = accS;
            P = accP;
        }
    }

    if (tid < 64) {
        sP[tid] = (float)P;
        sQ[tid] = (float)((double)ALPHA * S);
    }
    __syncthreads();

    // ---- Phase 2: streaming with register double-buffer ----
    for (;;) {
        const int nrow = row + stride;
        const bool more = (nrow < nrows);
        fx4 nx0, nx1, ny0, ny1;
        if (more) {
            const size_t np = (size_t)nrow * 2;
            nx0 = x4[np]; nx1 = x4[np + 1];
            ny0 = y4[np]; ny1 = y4[np + 1];
        }

        const float xs[8] = {cx0.x, cx0.y, cx0.z, cx0.w,
                             cx1.x, cx1.y, cx1.z, cx1.w};
        const float ys[8] = {cy0.x, cy0.y, cy0.z, cy0.w,
                             cy1.x, cy1.y, cy1.z, cy1.w};
        float ov[8];
#pragma unroll
        for (int jj = 0; jj < 8; ++jj) {
            float acc = 0.0f;
#pragma unroll
            for (int t = 0; t < 8; ++t) acc = fmaf(xs[t], sP[t * 8 + jj], acc);
#pragma unroll
            for (int t = 0; t < 8; ++t) acc = fmaf(ys[t], sQ[t * 8 + jj], acc);
            ov[jj] = acc;
        }
        fx4 o0 = {ov[0], ov[1], ov[2], ov[3]};
        fx4 o1 = {ov[4], ov[5], ov[6], ov[7]};
        out4[p]     = o0;
        out4[p + 1] = o1;

        if (!more) break;
        row = nrow;
        p = (size_t)row * 2;
        cx0 = nx0; cx1 = nx1; cy0 = ny0; cy1 = ny1;
    }
}

extern "C" void kernel_launch(void* const* d_in, const int* in_sizes, int n_in,
                              void* d_out, int out_size, void* d_ws, size_t ws_size,
                              hipStream_t stream) {
    const float* x = (const float*)d_in[0];
    const float* y = (const float*)d_in[1];
    const float* A = (const float*)d_in[2];
    float* out = (float*)d_out;

    const int nrows = in_sizes[0] / 8;  // 2,000,000

    fused_apply<<<NBLK, BLK, 0, stream>>>((const fx4*)x, (const fx4*)y, A,
                                          (fx4*)out, nrows);
}

// Round 8
// 33.217 us; speedup vs baseline: 7.8973x; 1.1086x over previous
//
#include <hip/hip_runtime.h>

#define ALPHA 0.002
#define NBLK 1280   // 5 blocks/CU on 256 CUs — all resident at ~88 VGPR
#define BLK  256

typedef float fx4 __attribute__((ext_vector_type(4)));

// Single fused kernel.
// Phase 1: tid<64 redundantly compute P = M^100, Q = ALPHA*sum M^k
//          (M = I - ALPHA*A) via binary doubling in fp64, publish fp32 in LDS.
// Phase 1b: A (hence P, Q) is CIRCULANT: P[t][j] = cP[(j-t)&7] where
//          cP = row 0 of P. Pull cP/cQ (16 scalars) into SGPRs via
//          readfirstlane -> the streaming loop does ZERO LDS reads.
//          (R7 analysis: per-row LDS broadcast reads were the hidden
//          per-CU-pipe bottleneck: ~90K cyc/CU ~= the whole kernel time.)
// Phase 2: grid-stride streaming, register double-buffer:
//          out[row][j] = sum_t x[t]*cP[(j-t)&7] + y[t]*cQ[(j-t)&7].
__global__ __launch_bounds__(BLK) void fused_apply(const fx4* __restrict__ x4,
                                                   const fx4* __restrict__ y4,
                                                   const float* __restrict__ A,
                                                   fx4* __restrict__ out4,
                                                   int nrows) {
    __shared__ double Ms[64];
    __shared__ double Ps[64];
    __shared__ double Ss[64];
    __shared__ float sP[64];
    __shared__ float sQ[64];

    const int tid = threadIdx.x;
    const int stride = NBLK * BLK;

    // ---- Phase 0: issue first row's loads early (hide PQ latency) ----
    int row = blockIdx.x * BLK + tid;          // < nrows (327680 < 2M)
    size_t p = (size_t)row * 2;
    fx4 cx0 = x4[p], cx1 = x4[p + 1];
    fx4 cy0 = y4[p], cy1 = y4[p + 1];

    // ---- Phase 1: per-block P/Q via binary doubling (tid<64 active) ----
    const int i = tid >> 3, j = tid & 7;
    if (tid < 64)
        Ms[tid] = ((i == j) ? 1.0 : 0.0) - (double)ALPHA * (double)A[tid];
    __syncthreads();

    double Mcol[8];
    if (tid < 64) {
#pragma unroll
        for (int t = 0; t < 8; ++t) Mcol[t] = Ms[t * 8 + j];
    }

    double P = (i == j) ? 1.0 : 0.0;  // garbage for tid>=64, unused
    double S = 0.0;
    const int bits[7] = {1, 1, 0, 0, 1, 0, 0};  // 100 = 0b1100100

#pragma unroll
    for (int b = 0; b < 7; ++b) {
        if (tid < 64) { Ps[tid] = P; Ss[tid] = S; }
        __syncthreads();
        double accS = S, accP = 0.0;
        if (tid < 64) {
#pragma unroll
            for (int t = 0; t < 8; ++t) {
                const double pit = Ps[i * 8 + t];
                accS += pit * Ss[t * 8 + j];   // S + P*S
                accP += pit * Ps[t * 8 + j];   // P*P
            }
        }
        __syncthreads();
        if (bits[b]) {
            if (tid < 64) { S = accS + accP; Ps[tid] = accP; }
            __syncthreads();
            if (tid < 64) {
                double p2 = 0.0;
#pragma unroll
                for (int t = 0; t < 8; ++t) p2 += Ps[i * 8 + t] * Mcol[t];
                P = p2;
            }
            __syncthreads();
        } else {
            S = accS;
            P = accP;
        }
    }

    if (tid < 64) {
        sP[tid] = (float)P;
        sQ[tid] = (float)((double)ALPHA * S);
    }
    __syncthreads();

    // ---- Phase 1b: circulant row 0 -> SGPRs (wave-uniform) ----
    float cP[8], cQ[8];
#pragma unroll
    for (int k = 0; k < 8; ++k) {
        cP[k] = __int_as_float(__builtin_amdgcn_readfirstlane(__float_as_int(sP[k])));
        cQ[k] = __int_as_float(__builtin_amdgcn_readfirstlane(__float_as_int(sQ[k])));
    }

    // ---- Phase 2: streaming with register double-buffer, LDS-free ----
    for (;;) {
        const int nrow = row + stride;
        const bool more = (nrow < nrows);
        fx4 nx0, nx1, ny0, ny1;
        if (more) {
            const size_t np = (size_t)nrow * 2;
            nx0 = x4[np]; nx1 = x4[np + 1];
            ny0 = y4[np]; ny1 = y4[np + 1];
        }

        const float xs[8] = {cx0.x, cx0.y, cx0.z, cx0.w,
                             cx1.x, cx1.y, cx1.z, cx1.w};
        const float ys[8] = {cy0.x, cy0.y, cy0.z, cy0.w,
                             cy1.x, cy1.y, cy1.z, cy1.w};
        float ov[8];
#pragma unroll
        for (int jj = 0; jj < 8; ++jj) {
            float acc = 0.0f;
#pragma unroll
            for (int t = 0; t < 8; ++t) {
                const int k = (jj - t) & 7;          // compile-time constant
                acc = fmaf(xs[t], cP[k], acc);
                acc = fmaf(ys[t], cQ[k], acc);
            }
            ov[jj] = acc;
        }
        fx4 o0 = {ov[0], ov[1], ov[2], ov[3]};
        fx4 o1 = {ov[4], ov[5], ov[6], ov[7]};
        out4[p]     = o0;
        out4[p + 1] = o1;

        if (!more) break;
        row = nrow;
        p = (size_t)row * 2;
        cx0 = nx0; cx1 = nx1; cy0 = ny0; cy1 = ny1;
    }
}

extern "C" void kernel_launch(void* const* d_in, const int* in_sizes, int n_in,
                              void* d_out, int out_size, void* d_ws, size_t ws_size,
                              hipStream_t stream) {
    const float* x = (const float*)d_in[0];
    const float* y = (const float*)d_in[1];
    const float* A = (const float*)d_in[2];
    float* out = (float*)d_out;

    const int nrows = in_sizes[0] / 8;  // 2,000,000

    fused_apply<<<NBLK, BLK, 0, stream>>>((const fx4*)x, (const fx4*)y, A,
                                          (fx4*)out, nrows);
}

// Round 9
// 33.159 us; speedup vs baseline: 7.9109x; 1.0017x over previous
//
#include <hip/hip_runtime.h>

#define ALPHA 0.002
#define NBLK 2048   // 8 blocks/CU on 256 CUs — all resident at 40 VGPR (R8 build)
#define BLK  256

typedef float fx4 __attribute__((ext_vector_type(4)));

// Single fused kernel.
// Phase 1: tid<64 redundantly compute P = M^100, Q = ALPHA*sum M^k
//          (M = I - ALPHA*A) via binary doubling in fp64, publish fp32 in LDS.
// Phase 1b: A (hence P, Q) is CIRCULANT: P[t][j] = cP[(j-t)&7] where
//          cP = row 0 of P. Pull cP/cQ (16 scalars) into SGPRs via
//          readfirstlane -> the streaming loop does ZERO LDS reads.
//          (R8 confirmed: LDS broadcast-read issue rate was the bottleneck;
//          removing it: 36.8 -> 33.2 us, VGPR 88 -> 40.)
// Phase 2: grid-stride streaming, register double-buffer:
//          out[row][j] = sum_t x[t]*cP[(j-t)&7] + y[t]*cQ[(j-t)&7].
// NBLK=2048 matches the 40-VGPR build's 8-blocks/CU residency (R8 ran 1280,
// leaving 3 waves/SIMD unused). No min-waves launch_bounds (R6 lesson).
__global__ __launch_bounds__(BLK) void fused_apply(const fx4* __restrict__ x4,
                                                   const fx4* __restrict__ y4,
                                                   const float* __restrict__ A,
                                                   fx4* __restrict__ out4,
                                                   int nrows) {
    __shared__ double Ms[64];
    __shared__ double Ps[64];
    __shared__ double Ss[64];
    __shared__ float sP[64];
    __shared__ float sQ[64];

    const int tid = threadIdx.x;
    const int stride = NBLK * BLK;

    // ---- Phase 0: issue first row's loads early (hide PQ latency) ----
    int row = blockIdx.x * BLK + tid;          // < nrows (524288 < 2M)
    size_t p = (size_t)row * 2;
    fx4 cx0 = x4[p], cx1 = x4[p + 1];
    fx4 cy0 = y4[p], cy1 = y4[p + 1];

    // ---- Phase 1: per-block P/Q via binary doubling (tid<64 active) ----
    const int i = tid >> 3, j = tid & 7;
    if (tid < 64)
        Ms[tid] = ((i == j) ? 1.0 : 0.0) - (double)ALPHA * (double)A[tid];
    __syncthreads();

    double Mcol[8];
    if (tid < 64) {
#pragma unroll
        for (int t = 0; t < 8; ++t) Mcol[t] = Ms[t * 8 + j];
    }

    double P = (i == j) ? 1.0 : 0.0;  // garbage for tid>=64, unused
    double S = 0.0;
    const int bits[7] = {1, 1, 0, 0, 1, 0, 0};  // 100 = 0b1100100

#pragma unroll
    for (int b = 0; b < 7; ++b) {
        if (tid < 64) { Ps[tid] = P; Ss[tid] = S; }
        __syncthreads();
        double accS = S, accP = 0.0;
        if (tid < 64) {
#pragma unroll
            for (int t = 0; t < 8; ++t) {
                const double pit = Ps[i * 8 + t];
                accS += pit * Ss[t * 8 + j];   // S + P*S
                accP += pit * Ps[t * 8 + j];   // P*P
            }
        }
        __syncthreads();
        if (bits[b]) {
            if (tid < 64) { S = accS + accP; Ps[tid] = accP; }
            __syncthreads();
            if (tid < 64) {
                double p2 = 0.0;
#pragma unroll
                for (int t = 0; t < 8; ++t) p2 += Ps[i * 8 + t] * Mcol[t];
                P = p2;
            }
            __syncthreads();
        } else {
            S = accS;
            P = accP;
        }
    }

    if (tid < 64) {
        sP[tid] = (float)P;
        sQ[tid] = (float)((double)ALPHA * S);
    }
    __syncthreads();

    // ---- Phase 1b: circulant row 0 -> SGPRs (wave-uniform) ----
    float cP[8], cQ[8];
#pragma unroll
    for (int k = 0; k < 8; ++k) {
        cP[k] = __int_as_float(__builtin_amdgcn_readfirstlane(__float_as_int(sP[k])));
        cQ[k] = __int_as_float(__builtin_amdgcn_readfirstlane(__float_as_int(sQ[k])));
    }

    // ---- Phase 2: streaming with register double-buffer, LDS-free ----
    for (;;) {
        const int nrow = row + stride;
        const bool more = (nrow < nrows);
        fx4 nx0, nx1, ny0, ny1;
        if (more) {
            const size_t np = (size_t)nrow * 2;
            nx0 = x4[np]; nx1 = x4[np + 1];
            ny0 = y4[np]; ny1 = y4[np + 1];
        }

        const float xs[8] = {cx0.x, cx0.y, cx0.z, cx0.w,
                             cx1.x, cx1.y, cx1.z, cx1.w};
        const float ys[8] = {cy0.x, cy0.y, cy0.z, cy0.w,
                             cy1.x, cy1.y, cy1.z, cy1.w};
        float ov[8];
#pragma unroll
        for (int jj = 0; jj < 8; ++jj) {
            float acc = 0.0f;
#pragma unroll
            for (int t = 0; t < 8; ++t) {
                const int k = (jj - t) & 7;          // compile-time constant
                acc = fmaf(xs[t], cP[k], acc);
                acc = fmaf(ys[t], cQ[k], acc);
            }
            ov[jj] = acc;
        }
        fx4 o0 = {ov[0], ov[1], ov[2], ov[3]};
        fx4 o1 = {ov[4], ov[5], ov[6], ov[7]};
        out4[p]     = o0;
        out4[p + 1] = o1;

        if (!more) break;
        row = nrow;
        p = (size_t)row * 2;
        cx0 = nx0; cx1 = nx1; cy0 = ny0; cy1 = ny1;
    }
}

extern "C" void kernel_launch(void* const* d_in, const int* in_sizes, int n_in,
                              void* d_out, int out_size, void* d_ws, size_t ws_size,
                              hipStream_t stream) {
    const float* x = (const float*)d_in[0];
    const float* y = (const float*)d_in[1];
    const float* A = (const float*)d_in[2];
    float* out = (float*)d_out;

    const int nrows = in_sizes[0] / 8;  // 2,000,000

    fused_apply<<<NBLK, BLK, 0, stream>>>((const fx4*)x, (const fx4*)y, A,
                                          (fx4*)out, nrows);
}